// Round 5
// baseline (209.435 us; speedup 1.0000x reference)
//
#include <hip/hip_runtime.h>
#include <hip/hip_bf16.h>
#include <stdint.h>

// Problem constants
#define Bn  4
#define Nn  10000
#define KRn 5
#define KAn 8
#define Cn  32
#define On  64
#define Kk  2
#define RN  8                  // rotations = KA
#define MT  32                 // points per block
#define LDX 264                // LDS row stride (bf16 elems): 256 + 8 pad

typedef __attribute__((ext_vector_type(8))) short bf16x8;
typedef __attribute__((ext_vector_type(4))) float f32x4;
typedef __attribute__((ext_vector_type(2))) float f32x2;

static __device__ __forceinline__ unsigned int bfpack2(float a, float b) {
  unsigned int ua = __builtin_bit_cast(unsigned int, a);
  unsigned int ub = __builtin_bit_cast(unsigned int, b);
  ua = (ua + 0x7FFFu + ((ua >> 16) & 1u)) >> 16;
  ub = (ub + 0x7FFFu + ((ub >> 16) & 1u)) >> 16;
  return ua | (ub << 16);
}
static __device__ __forceinline__ unsigned short bf1(float a) {
  unsigned int ua = __builtin_bit_cast(unsigned int, a);
  return (unsigned short)((ua + 0x7FFFu + ((ua >> 16) & 1u)) >> 16);
}

// Un-rotated summed kernel, B-fragment-ready:
//   wk[p][q'][ot][lane][j] = sum_g kernels[g, p, q', o, c]
//   o = ot*16 + (lane&15), c = (lane>>4)*8 + j
__global__ void prep_kernel(const float* __restrict__ kernels,
                            const float* __restrict__ bias,
                            unsigned short* __restrict__ wk,
                            float* __restrict__ bconst) {
  int tid = blockIdx.x * 256 + threadIdx.x;
  if (tid < KRn * KAn * 4 * 64) {
    int lane = tid & 63;
    int ot   = (tid >> 6) & 3;
    int q    = (tid >> 8) & 7;
    int p    = tid >> 11;
    int o  = ot * 16 + (lane & 15);
    int cb = (lane >> 4) * 8;
    const float* k0 = kernels + (((p * KAn + q) * On + o) * Cn + cb);
    const float* k1 = k0 + KRn * KAn * On * Cn;  // g=1
    unsigned short v[8];
#pragma unroll
    for (int j = 0; j < 8; ++j) v[j] = bf1(k0[j] + k1[j]);
    reinterpret_cast<bf16x8*>(wk)[tid] = *reinterpret_cast<const bf16x8*>(v);
  }
  if (blockIdx.x == 0 && threadIdx.x < On) {
    float s = 0.f;
    for (int pq = 0; pq < KRn * KAn; ++pq) s += bias[pq * On + (int)threadIdx.x];
    bconst[threadIdx.x] = (float)Kk * s;
  }
}

// Fused gather+interp + MFMA GEMM, 3-depth software pipeline:
//   bary: regs one chunk ahead -> bs LDS (dbuf)
//   signal gathers: k-pair interleaved between GEMM q-steps
//   W frags: issued one q-step ahead (FIFO vmcnt decoupling from gathers)
__global__ __launch_bounds__(256, 3) void conv_kernel(
    const float* __restrict__ signal,
    const float* __restrict__ bary,
    const unsigned short* __restrict__ wk,
    const float* __restrict__ bconst,
    float* __restrict__ out) {
  __shared__ __align__(16) unsigned short xs[2][MT * LDX];  // 2 x 16.5 KB
  __shared__ __align__(16) float bs[2][MT * 48];            // 2 x 6 KB

  const int b    = blockIdx.y;
  const int m0   = blockIdx.x * MT;
  const int tid  = threadIdx.x;
  const int lane = tid & 63;
  const int wv   = tid >> 6;           // wave 0..3
  const int lm   = lane & 15;
  const int lg   = lane >> 4;

  const float* sigb = signal + (size_t)b * Nn * Cn;
  const bf16x8* wkf = reinterpret_cast<const bf16x8*>(wk);

  // interp identity: 8-lane group owns one (pt, q); lane cv handles 16B of channels
  const int sq  = lane >> 3;           // q of this group
  const int cv4 = (lane & 7) * 4;      // channel offset (floats)
  // bary identity: thread (bpt, bc8) loads 6 contiguous floats
  const int bpt = tid >> 3;            // 0..31 point
  const int bc8 = tid & 7;             // 0..7  q
  const int bn  = m0 + bpt;
  const bool bvalid = bn < Nn;
  const float* bybase = bary + (size_t)b * Nn * 240 + (size_t)bn * 240 + bc8 * 6;

  f32x2 br0, br1, br2;                 // bary chunk prefetch regs
  f32x4 sg[8][3];                      // gather in-flight (statically indexed)
  float wgt[8][3];
  bf16x8 Bfr[2][4];                    // W frags, 2-deep

#define BR(PP) do {                                                            \
    if (bvalid) {                                                              \
      const float* s_ = bybase + (PP) * 48;                                    \
      br0 = *(const f32x2*)(s_);                                               \
      br1 = *(const f32x2*)(s_ + 2);                                           \
      br2 = *(const f32x2*)(s_ + 4);                                           \
    } else { br0 = (f32x2){0.f, 0.f}; br1 = br0; br2 = br0; }                  \
  } while (0)

#define BW(PP) do {                                                            \
    float* d_ = &bs[(PP) & 1][bpt * 48 + bc8 * 6];                             \
    *(f32x2*)(d_) = br0; *(f32x2*)(d_ + 2) = br1; *(f32x2*)(d_ + 4) = br2;     \
  } while (0)

#define SS(K, SB) do {                                                         \
    const float* bb_ = &bs[SB][((K) * 4 + wv) * 48 + sq * 6];                  \
    f32x2 p0 = *(const f32x2*)(bb_);                                           \
    f32x2 p1 = *(const f32x2*)(bb_ + 2);                                       \
    f32x2 p2 = *(const f32x2*)(bb_ + 4);                                       \
    sg[K][0] = *(const f32x4*)(sigb + (size_t)(int)p0.x * Cn + cv4);           \
    wgt[K][0] = p0.y;                                                          \
    sg[K][1] = *(const f32x4*)(sigb + (size_t)(int)p1.x * Cn + cv4);           \
    wgt[K][1] = p1.y;                                                          \
    sg[K][2] = *(const f32x4*)(sigb + (size_t)(int)p2.x * Cn + cv4);           \
    wgt[K][2] = p2.y;                                                          \
  } while (0)

#define SP(K, SB) do {                                                         \
    f32x4 v_ = wgt[K][0] * sg[K][0] + wgt[K][1] * sg[K][1] +                   \
               wgt[K][2] * sg[K][2];                                           \
    unsigned long long pk_ = (unsigned long long)bfpack2(v_.x, v_.y) |         \
                             ((unsigned long long)bfpack2(v_.z, v_.w) << 32);  \
    *(unsigned long long*)(&xs[SB][((K) * 4 + wv) * LDX + sq * 32 + cv4]) = pk_;\
  } while (0)

#define BF(P_, QP, BUF) do {                                                   \
    const bf16x8* wp_ = wkf + (size_t)((P_) * 8 + (QP)) * 256 + lane;          \
    Bfr[BUF][0] = wp_[0];   Bfr[BUF][1] = wp_[64];                             \
    Bfr[BUF][2] = wp_[128]; Bfr[BUF][3] = wp_[192];                            \
  } while (0)

#define G(QP, BUF, PB) do {                                                    \
    _Pragma("unroll")                                                          \
    for (int rr = 0; rr < 2; ++rr) {                                           \
      int q_ = ((QP) - (wv * 2 + rr)) & 7;                                     \
      _Pragma("unroll")                                                        \
      for (int mt = 0; mt < 2; ++mt) {                                         \
        bf16x8 a_ = *(const bf16x8*)(&xs[PB][(mt * 16 + lm) * LDX + q_ * 32 + lg * 8]); \
        _Pragma("unroll")                                                      \
        for (int ot = 0; ot < 4; ++ot)                                         \
          acc[rr][ot][mt] = __builtin_amdgcn_mfma_f32_16x16x32_bf16(           \
              a_, Bfr[BUF][ot], acc[rr][ot][mt], 0, 0, 0);                     \
      }                                                                        \
    }                                                                          \
  } while (0)

  // ---- prologue: bary chunks 0,1 -> bs; full-stage chunk 0 -> xs[0] ----
  BR(0); BW(0);
  BR(1); BW(1);
  __syncthreads();
  SS(0, 0); SS(1, 0); SS(2, 0); SS(3, 0);
  SS(4, 0); SS(5, 0); SS(6, 0); SS(7, 0);
  SP(0, 0); SP(1, 0); SP(2, 0); SP(3, 0);
  SP(4, 0); SP(5, 0); SP(6, 0); SP(7, 0);

  f32x4 acc[2][4][2];                  // [rr][ot][mt]
#pragma unroll
  for (int rr = 0; rr < 2; ++rr)
#pragma unroll
    for (int ot = 0; ot < 4; ++ot)
#pragma unroll
      for (int mt = 0; mt < 2; ++mt) acc[rr][ot][mt] = (f32x4){0.f, 0.f, 0.f, 0.f};

  // ---- main loop: GEMM(p) interleaved with staging chunk p+1 ----
  for (int p = 0; p < KRn - 1; ++p) {
    __syncthreads();                   // xs[p&1] staged, xs[sb] free, bs[sb] ready
    const int pb = p & 1;
    const int sb = pb ^ 1;             // = (p+1)&1 : bs read + xs write parity
    if (p < KRn - 2) BR(p + 2);        // HBM lead = one full chunk

    BF(p, 0, 0);
    SS(0, sb); SS(1, sb);
    G(0, 0, pb);
    BF(p, 1, 1); SP(0, sb); SS(2, sb); SP(1, sb); SS(3, sb);
    G(1, 1, pb);
    BF(p, 2, 0); SP(2, sb); SS(4, sb); SP(3, sb); SS(5, sb);
    G(2, 0, pb);
    BF(p, 3, 1); SP(4, sb); SS(6, sb); SP(5, sb); SS(7, sb);
    G(3, 1, pb);
    BF(p, 4, 0); SP(6, sb); SP(7, sb);
    G(4, 0, pb);
    BF(p, 5, 1);
    G(5, 1, pb);
    BF(p, 6, 0);
    G(6, 0, pb);
    BF(p, 7, 1);
    G(7, 1, pb);

    if (p < KRn - 2) BW(p + 2);
  }

  // ---- peeled final GEMM (chunk 4, xs[0]) ----
  __syncthreads();
  {
    const int p = KRn - 1, pb = p & 1;
    BF(p, 0, 0); G(0, 0, pb);
    BF(p, 1, 1); G(1, 1, pb);
    BF(p, 2, 0); G(2, 0, pb);
    BF(p, 3, 1); G(3, 1, pb);
    BF(p, 4, 0); G(4, 0, pb);
    BF(p, 5, 1); G(5, 1, pb);
    BF(p, 6, 0); G(6, 0, pb);
    BF(p, 7, 1); G(7, 1, pb);
  }

  // ---- epilogue: out[b, r, n, o] = acc + bconst[o] ----
#pragma unroll
  for (int rr = 0; rr < 2; ++rr) {
    int r = wv * 2 + rr;
#pragma unroll
    for (int ot = 0; ot < 4; ++ot) {
      int o = ot * 16 + lm;
      float bc = bconst[o];
      float* outp = out + (((size_t)b * RN + r) * Nn) * On + o;
#pragma unroll
      for (int mt = 0; mt < 2; ++mt) {
        int nbase = m0 + mt * 16 + lg * 4;
#pragma unroll
        for (int i = 0; i < 4; ++i) {
          int n = nbase + i;
          if (n < Nn) outp[(size_t)n * On] = acc[rr][ot][mt][i] + bc;
        }
      }
    }
  }
#undef BR
#undef BW
#undef SS
#undef SP
#undef BF
#undef G
}

extern "C" void kernel_launch(void* const* d_in, const int* in_sizes, int n_in,
                              void* d_out, int out_size, void* d_ws, size_t ws_size,
                              hipStream_t stream) {
  const float* signal  = (const float*)d_in[0];
  const float* bary    = (const float*)d_in[1];
  const float* kernels = (const float*)d_in[2];
  const float* bias    = (const float*)d_in[3];
  float* out = (float*)d_out;

  unsigned short* wk = (unsigned short*)d_ws;
  float* bconst = (float*)((char*)d_ws + (size_t)KRn * KAn * 4 * 64 * 8 * 2);

  hipLaunchKernelGGL(prep_kernel, dim3(40), dim3(256), 0, stream,
                     kernels, bias, wk, bconst);
  dim3 grid((Nn + MT - 1) / MT, Bn);
  hipLaunchKernelGGL(conv_kernel, grid, dim3(256), 0, stream,
                     signal, bary, wk, bconst, out);
}